// Round 2
// baseline (1151.997 us; speedup 1.0000x reference)
//
#include <hip/hip_runtime.h>
#include <hip/hip_bf16.h>

#define N_NODES 25000
#define N_EDGES 400000

__device__ __forceinline__ float silu_f(float x) { return x / (1.0f + __expf(-x)); }

// ---------------------------------------------------------------------------
// Embedding: h = silu([h_g0|h_g1] @ Wg1 + bg1) @ Wg2 + bg2
// h_g1 = base - s (group element -I), one dot product serves both channels.
// ---------------------------------------------------------------------------
__global__ __launch_bounds__(256) void k_embed(
    const float* __restrict__ nodes, const float* __restrict__ W_emb, const float* __restrict__ b_emb,
    const float* __restrict__ Wg1, const float* __restrict__ bg1,
    const float* __restrict__ Wg2, const float* __restrict__ bg2,
    float* __restrict__ h)
{
  __shared__ float We[5 * 64];
  __shared__ float W1[128 * 64];
  __shared__ float W2[64 * 64];
  __shared__ float be[64], b1s[64], b2s[64];
  __shared__ __align__(16) float hbuf[4][128];
  __shared__ __align__(16) float tbuf[4][64];

  for (int t = threadIdx.x; t < 128 * 64; t += 256) W1[t] = Wg1[t];
  for (int t = threadIdx.x; t < 64 * 64; t += 256) W2[t] = Wg2[t];
  for (int t = threadIdx.x; t < 5 * 64; t += 256) We[t] = W_emb[t];
  if (threadIdx.x < 64) {
    be[threadIdx.x]  = b_emb[threadIdx.x];
    b1s[threadIdx.x] = bg1[threadIdx.x];
    b2s[threadIdx.x] = bg2[threadIdx.x];
  }
  __syncthreads();

  const int lane = threadIdx.x & 63;
  const int wv = threadIdx.x >> 6;
  float* hb = hbuf[wv];
  float* tb = tbuf[wv];
  const float4* hb4 = (const float4*)hb;
  const float4* tb4 = (const float4*)tb;

  int n0 = blockIdx.x * 32 + wv * 8;
  int n1 = min(n0 + 8, N_NODES);
  for (int n = n0; n < n1; ++n) {
    float x0 = nodes[n * 5 + 0], x1 = nodes[n * 5 + 1],
          x2 = nodes[n * 5 + 2], x3 = nodes[n * 5 + 3],
          x4 = nodes[n * 5 + 4];
    float w0 = We[0 * 64 + lane], w1 = We[1 * 64 + lane], w2 = We[2 * 64 + lane],
          w3 = We[3 * 64 + lane], w4 = We[4 * 64 + lane];
    float base = be[lane] + x4 * w4;
    float s = x0 * w0 + x1 * w1 + x2 * w2 + x3 * w3;
    hb[lane] = base + s;       // group element 0 (identity)
    hb[64 + lane] = base - s;  // group element 1 (-I)
    __builtin_amdgcn_wave_barrier();

    float t = b1s[lane];
#pragma unroll
    for (int k4 = 0; k4 < 32; ++k4) {
      float4 hh = hb4[k4];
      t += hh.x * W1[(4 * k4 + 0) * 64 + lane];
      t += hh.y * W1[(4 * k4 + 1) * 64 + lane];
      t += hh.z * W1[(4 * k4 + 2) * 64 + lane];
      t += hh.w * W1[(4 * k4 + 3) * 64 + lane];
    }
    t = silu_f(t);
    __builtin_amdgcn_wave_barrier();
    tb[lane] = t;
    __builtin_amdgcn_wave_barrier();

    float o = b2s[lane];
#pragma unroll
    for (int k4 = 0; k4 < 16; ++k4) {
      float4 tt = tb4[k4];
      o += tt.x * W2[(4 * k4 + 0) * 64 + lane];
      o += tt.y * W2[(4 * k4 + 1) * 64 + lane];
      o += tt.z * W2[(4 * k4 + 2) * 64 + lane];
      o += tt.w * W2[(4 * k4 + 3) * 64 + lane];
    }
    h[n * 64 + lane] = o;
    __builtin_amdgcn_wave_barrier();
  }
}

// ---------------------------------------------------------------------------
// Per-layer node precompute: u = h @ eW1[0:64], v = h @ eW1[64:128]
// (factorization of the gathered edge GEMM1). Weight columns live in VGPRs.
// ---------------------------------------------------------------------------
__global__ __launch_bounds__(256) void k_node_pre(
    const float* __restrict__ h, const float* __restrict__ eW1,
    float* __restrict__ u, float* __restrict__ v)
{
  const int lane = threadIdx.x & 63;
  const int wv = threadIdx.x >> 6;
  float ar[64], br[64];
#pragma unroll
  for (int k = 0; k < 64; ++k) {
    ar[k] = eW1[k * 64 + lane];
    br[k] = eW1[(64 + k) * 64 + lane];
  }
  __shared__ __align__(16) float hbuf[4][64];
  float* hb = hbuf[wv];
  const float4* hb4 = (const float4*)hb;

  int nw = gridDim.x * 4;
  int wid = blockIdx.x * 4 + wv;
  int per = (N_NODES + nw - 1) / nw;
  int n0 = wid * per, n1 = min(N_NODES, n0 + per);
  for (int n = n0; n < n1; ++n) {
    hb[lane] = h[n * 64 + lane];
    __builtin_amdgcn_wave_barrier();
    float uu = 0.f, vv = 0.f;
#pragma unroll
    for (int k4 = 0; k4 < 16; ++k4) {
      float4 hh = hb4[k4];
      uu += hh.x * ar[4 * k4 + 0]; vv += hh.x * br[4 * k4 + 0];
      uu += hh.y * ar[4 * k4 + 1]; vv += hh.y * br[4 * k4 + 1];
      uu += hh.z * ar[4 * k4 + 2]; vv += hh.z * br[4 * k4 + 2];
      uu += hh.w * ar[4 * k4 + 3]; vv += hh.w * br[4 * k4 + 3];
    }
    u[n * 64 + lane] = uu;
    v[n * 64 + lane] = vv;
    __builtin_amdgcn_wave_barrier();
  }
}

// ---------------------------------------------------------------------------
// Per-layer fused edge kernel: t = silu(u[row]+v[col]+ea*w+b1);
// e = silu(t @ eW2 + b2); agg[row] += e  (one wave per edge, W2 col in VGPRs)
// ---------------------------------------------------------------------------
__global__ __launch_bounds__(256) void k_edge(
    const float* __restrict__ u, const float* __restrict__ v,
    const float* __restrict__ eatt, const int* __restrict__ rows, const int* __restrict__ cols,
    const float* __restrict__ wea, const float* __restrict__ eb1,
    const float* __restrict__ W2, const float* __restrict__ eb2,
    float* __restrict__ agg)
{
  const int lane = threadIdx.x & 63;
  const int wv = threadIdx.x >> 6;
  float w2r[64];
#pragma unroll
  for (int k = 0; k < 64; ++k) w2r[k] = W2[k * 64 + lane];
  float we = wea[lane];
  float b1v = eb1[lane];
  float b2v = eb2[lane];

  __shared__ __align__(16) float tbuf[4][64];
  float* tb = tbuf[wv];
  const float4* tb4 = (const float4*)tb;

  int nw = gridDim.x * 4;
  int wid = blockIdx.x * 4 + wv;
  int per = (N_EDGES + nw - 1) / nw;
  int e0 = wid * per, e1 = min(N_EDGES, e0 + per);
  for (int e = e0; e < e1; ++e) {
    int r = rows[e], c = cols[e];
    float ea = eatt[e];
    float t = u[r * 64 + lane] + v[c * 64 + lane] + ea * we + b1v;
    t = silu_f(t);
    tb[lane] = t;
    __builtin_amdgcn_wave_barrier();
    float acc = b2v;
#pragma unroll
    for (int k4 = 0; k4 < 16; ++k4) {
      float4 tt = tb4[k4];
      acc += tt.x * w2r[4 * k4 + 0];
      acc += tt.y * w2r[4 * k4 + 1];
      acc += tt.z * w2r[4 * k4 + 2];
      acc += tt.w * w2r[4 * k4 + 3];
    }
    float ev = silu_f(acc);
    unsafeAtomicAdd(&agg[r * 64 + lane], ev);  // HW global_atomic_add_f32
    __builtin_amdgcn_wave_barrier();
  }
}

// ---------------------------------------------------------------------------
// Per-layer node MLP: h = silu(h@nW1[0:64] + agg@nW1[64:128] + nb1) @ nW2 + nb2
// (in place; each node touched by exactly one wave)
// ---------------------------------------------------------------------------
__global__ __launch_bounds__(256, 2) void k_node_post(
    float* __restrict__ h, const float* __restrict__ agg,
    const float* __restrict__ nW1, const float* __restrict__ nb1,
    const float* __restrict__ nW2, const float* __restrict__ nb2)
{
  const int lane = threadIdx.x & 63;
  const int wv = threadIdx.x >> 6;
  float ar[64], br[64], wr[64];
#pragma unroll
  for (int k = 0; k < 64; ++k) {
    ar[k] = nW1[k * 64 + lane];
    br[k] = nW1[(64 + k) * 64 + lane];
    wr[k] = nW2[k * 64 + lane];
  }
  float b1v = nb1[lane], b2v = nb2[lane];
  __shared__ __align__(16) float hbuf[4][64];
  __shared__ __align__(16) float abuf[4][64];
  __shared__ __align__(16) float tbuf[4][64];
  float* hb = hbuf[wv]; float* ab = abuf[wv]; float* tb = tbuf[wv];
  const float4* hb4 = (const float4*)hb;
  const float4* ab4 = (const float4*)ab;
  const float4* tb4 = (const float4*)tb;

  int nw = gridDim.x * 4;
  int wid = blockIdx.x * 4 + wv;
  int per = (N_NODES + nw - 1) / nw;
  int n0 = wid * per, n1 = min(N_NODES, n0 + per);
  for (int n = n0; n < n1; ++n) {
    hb[lane] = h[n * 64 + lane];
    ab[lane] = agg[n * 64 + lane];
    __builtin_amdgcn_wave_barrier();
    float t = b1v;
#pragma unroll
    for (int k4 = 0; k4 < 16; ++k4) {
      float4 hh = hb4[k4];
      float4 aa = ab4[k4];
      t += hh.x * ar[4 * k4 + 0] + aa.x * br[4 * k4 + 0];
      t += hh.y * ar[4 * k4 + 1] + aa.y * br[4 * k4 + 1];
      t += hh.z * ar[4 * k4 + 2] + aa.z * br[4 * k4 + 2];
      t += hh.w * ar[4 * k4 + 3] + aa.w * br[4 * k4 + 3];
    }
    t = silu_f(t);
    __builtin_amdgcn_wave_barrier();
    tb[lane] = t;
    __builtin_amdgcn_wave_barrier();
    float o = b2v;
#pragma unroll
    for (int k4 = 0; k4 < 16; ++k4) {
      float4 tt = tb4[k4];
      o += tt.x * wr[4 * k4 + 0];
      o += tt.y * wr[4 * k4 + 1];
      o += tt.z * wr[4 * k4 + 2];
      o += tt.w * wr[4 * k4 + 3];
    }
    h[n * 64 + lane] = o;
    __builtin_amdgcn_wave_barrier();
  }
}

// ---------------------------------------------------------------------------
// Final node MLP: out = silu(concat(h,agg) @ dnW1 + dnb1) @ dnW2 + dnb2, (N,4)
// All lanes redundantly hold a dnW2 column for m = lane&3; lanes 0..3 store.
// ---------------------------------------------------------------------------
__global__ __launch_bounds__(256, 2) void k_node_final(
    const float* __restrict__ h, const float* __restrict__ agg,
    const float* __restrict__ dnW1, const float* __restrict__ dnb1,
    const float* __restrict__ dnW2, const float* __restrict__ dnb2,
    float* __restrict__ out)
{
  const int lane = threadIdx.x & 63;
  const int wv = threadIdx.x >> 6;
  float ar[64], br[64], wr[64];
#pragma unroll
  for (int k = 0; k < 64; ++k) {
    ar[k] = dnW1[k * 64 + lane];
    br[k] = dnW1[(64 + k) * 64 + lane];
    wr[k] = dnW2[k * 4 + (lane & 3)];
  }
  float b1v = dnb1[lane];
  float b2v = dnb2[lane & 3];
  __shared__ __align__(16) float hbuf[4][64];
  __shared__ __align__(16) float abuf[4][64];
  __shared__ __align__(16) float tbuf[4][64];
  float* hb = hbuf[wv]; float* ab = abuf[wv]; float* tb = tbuf[wv];
  const float4* hb4 = (const float4*)hb;
  const float4* ab4 = (const float4*)ab;
  const float4* tb4 = (const float4*)tb;

  int nw = gridDim.x * 4;
  int wid = blockIdx.x * 4 + wv;
  int per = (N_NODES + nw - 1) / nw;
  int n0 = wid * per, n1 = min(N_NODES, n0 + per);
  for (int n = n0; n < n1; ++n) {
    hb[lane] = h[n * 64 + lane];
    ab[lane] = agg[n * 64 + lane];
    __builtin_amdgcn_wave_barrier();
    float t = b1v;
#pragma unroll
    for (int k4 = 0; k4 < 16; ++k4) {
      float4 hh = hb4[k4];
      float4 aa = ab4[k4];
      t += hh.x * ar[4 * k4 + 0] + aa.x * br[4 * k4 + 0];
      t += hh.y * ar[4 * k4 + 1] + aa.y * br[4 * k4 + 1];
      t += hh.z * ar[4 * k4 + 2] + aa.z * br[4 * k4 + 2];
      t += hh.w * ar[4 * k4 + 3] + aa.w * br[4 * k4 + 3];
    }
    t = silu_f(t);
    __builtin_amdgcn_wave_barrier();
    tb[lane] = t;
    __builtin_amdgcn_wave_barrier();
    float o = b2v;
#pragma unroll
    for (int k4 = 0; k4 < 16; ++k4) {
      float4 tt = tb4[k4];
      o += tt.x * wr[4 * k4 + 0];
      o += tt.y * wr[4 * k4 + 1];
      o += tt.z * wr[4 * k4 + 2];
      o += tt.w * wr[4 * k4 + 3];
    }
    if (lane < 4) out[n * 4 + lane] = o;
    __builtin_amdgcn_wave_barrier();
  }
}

extern "C" void kernel_launch(void* const* d_in, const int* in_sizes, int n_in,
                              void* d_out, int out_size, void* d_ws, size_t ws_size,
                              hipStream_t stream)
{
  const float* nodes = (const float*)d_in[0];
  const int*   edges = (const int*)d_in[1];
  const float* eatt  = (const float*)d_in[2];
  const float* W_emb = (const float*)d_in[3];
  const float* b_emb = (const float*)d_in[4];
  const float* Wg1   = (const float*)d_in[5];
  const float* bg1   = (const float*)d_in[6];
  const float* Wg2   = (const float*)d_in[7];
  const float* bg2   = (const float*)d_in[8];
  const float* eW1   = (const float*)d_in[9];
  const float* eb1   = (const float*)d_in[10];
  const float* eW2   = (const float*)d_in[11];
  const float* eb2   = (const float*)d_in[12];
  const float* nW1   = (const float*)d_in[13];
  const float* nb1   = (const float*)d_in[14];
  const float* nW2   = (const float*)d_in[15];
  const float* nb2   = (const float*)d_in[16];
  const float* deW1  = (const float*)d_in[17];
  const float* deb1  = (const float*)d_in[18];
  const float* deW2  = (const float*)d_in[19];
  const float* deb2  = (const float*)d_in[20];
  const float* dnW1  = (const float*)d_in[21];
  const float* dnb1  = (const float*)d_in[22];
  const float* dnW2  = (const float*)d_in[23];
  const float* dnb2  = (const float*)d_in[24];
  float* out = (float*)d_out;

  float* h   = (float*)d_ws;
  float* u   = h + N_NODES * 64;
  float* v   = u + N_NODES * 64;
  float* agg = v + N_NODES * 64;

  const int* rows = edges;
  const int* cols = edges + N_EDGES;

  k_embed<<<(N_NODES + 31) / 32, 256, 0, stream>>>(nodes, W_emb, b_emb, Wg1, bg1, Wg2, bg2, h);

  for (int i = 0; i < 5; ++i) {
    const float* W1i = eW1 + i * 129 * 64;
    k_node_pre<<<1024, 256, 0, stream>>>(h, W1i, u, v);
    hipMemsetAsync(agg, 0, N_NODES * 64 * sizeof(float), stream);
    k_edge<<<2048, 256, 0, stream>>>(u, v, eatt, rows, cols, W1i + 128 * 64,
                                     eb1 + i * 64, eW2 + i * 64 * 64, eb2 + i * 64, agg);
    k_node_post<<<1024, 256, 0, stream>>>(h, agg, nW1 + i * 128 * 64, nb1 + i * 64,
                                          nW2 + i * 64 * 64, nb2 + i * 64);
  }
  // decoder GCL
  k_node_pre<<<1024, 256, 0, stream>>>(h, deW1, u, v);
  hipMemsetAsync(agg, 0, N_NODES * 64 * sizeof(float), stream);
  k_edge<<<2048, 256, 0, stream>>>(u, v, eatt, rows, cols, deW1 + 128 * 64,
                                   deb1, deW2, deb2, agg);
  k_node_final<<<1024, 256, 0, stream>>>(h, agg, dnW1, dnb1, dnW2, dnb2, out);
}

// Round 3
// 997.807 us; speedup vs baseline: 1.1545x; 1.1545x over previous
//
#include <hip/hip_runtime.h>
#include <hip/hip_bf16.h>

#define N_NODES 25000
#define N_EDGES 400000

typedef __attribute__((ext_vector_type(8))) short short8;
typedef __attribute__((ext_vector_type(4))) float f32x4;

__device__ __forceinline__ float silu_f(float x) { return x / (1.0f + __expf(-x)); }

__device__ __forceinline__ short f2bf_s(float x) {
  __hip_bfloat16 h = __float2bfloat16(x);
  return *reinterpret_cast<short*>(&h);
}
__device__ __forceinline__ float bf_s2f(short s) {
  __hip_bfloat16 h = *reinterpret_cast<__hip_bfloat16*>(&s);
  return __bfloat162float(h);
}

// ---------------------------------------------------------------------------
// Embedding: h = silu([h_g0|h_g1] @ Wg1 + bg1) @ Wg2 + bg2
// ---------------------------------------------------------------------------
__global__ __launch_bounds__(256) void k_embed(
    const float* __restrict__ nodes, const float* __restrict__ W_emb, const float* __restrict__ b_emb,
    const float* __restrict__ Wg1, const float* __restrict__ bg1,
    const float* __restrict__ Wg2, const float* __restrict__ bg2,
    float* __restrict__ h)
{
  __shared__ float We[5 * 64];
  __shared__ float W1[128 * 64];
  __shared__ float W2[64 * 64];
  __shared__ float be[64], b1s[64], b2s[64];
  __shared__ __align__(16) float hbuf[4][128];
  __shared__ __align__(16) float tbuf[4][64];

  for (int t = threadIdx.x; t < 128 * 64; t += 256) W1[t] = Wg1[t];
  for (int t = threadIdx.x; t < 64 * 64; t += 256) W2[t] = Wg2[t];
  for (int t = threadIdx.x; t < 5 * 64; t += 256) We[t] = W_emb[t];
  if (threadIdx.x < 64) {
    be[threadIdx.x]  = b_emb[threadIdx.x];
    b1s[threadIdx.x] = bg1[threadIdx.x];
    b2s[threadIdx.x] = bg2[threadIdx.x];
  }
  __syncthreads();

  const int lane = threadIdx.x & 63;
  const int wv = threadIdx.x >> 6;
  float* hb = hbuf[wv];
  float* tb = tbuf[wv];
  const float4* hb4 = (const float4*)hb;
  const float4* tb4 = (const float4*)tb;

  int n0 = blockIdx.x * 32 + wv * 8;
  int n1 = min(n0 + 8, N_NODES);
  for (int n = n0; n < n1; ++n) {
    float x0 = nodes[n * 5 + 0], x1 = nodes[n * 5 + 1],
          x2 = nodes[n * 5 + 2], x3 = nodes[n * 5 + 3],
          x4 = nodes[n * 5 + 4];
    float w0 = We[0 * 64 + lane], w1 = We[1 * 64 + lane], w2 = We[2 * 64 + lane],
          w3 = We[3 * 64 + lane], w4 = We[4 * 64 + lane];
    float base = be[lane] + x4 * w4;
    float s = x0 * w0 + x1 * w1 + x2 * w2 + x3 * w3;
    hb[lane] = base + s;
    hb[64 + lane] = base - s;
    __builtin_amdgcn_wave_barrier();

    float t = b1s[lane];
#pragma unroll
    for (int k4 = 0; k4 < 32; ++k4) {
      float4 hh = hb4[k4];
      t += hh.x * W1[(4 * k4 + 0) * 64 + lane];
      t += hh.y * W1[(4 * k4 + 1) * 64 + lane];
      t += hh.z * W1[(4 * k4 + 2) * 64 + lane];
      t += hh.w * W1[(4 * k4 + 3) * 64 + lane];
    }
    t = silu_f(t);
    __builtin_amdgcn_wave_barrier();
    tb[lane] = t;
    __builtin_amdgcn_wave_barrier();

    float o = b2s[lane];
#pragma unroll
    for (int k4 = 0; k4 < 16; ++k4) {
      float4 tt = tb4[k4];
      o += tt.x * W2[(4 * k4 + 0) * 64 + lane];
      o += tt.y * W2[(4 * k4 + 1) * 64 + lane];
      o += tt.z * W2[(4 * k4 + 2) * 64 + lane];
      o += tt.w * W2[(4 * k4 + 3) * 64 + lane];
    }
    h[n * 64 + lane] = o;
    __builtin_amdgcn_wave_barrier();
  }
}

// ---------------------------------------------------------------------------
// Per-layer node precompute: u = h @ eW1[0:64], v = h @ eW1[64:128]
// ---------------------------------------------------------------------------
__global__ __launch_bounds__(256) void k_node_pre(
    const float* __restrict__ h, const float* __restrict__ eW1,
    float* __restrict__ u, float* __restrict__ v)
{
  const int lane = threadIdx.x & 63;
  const int wv = threadIdx.x >> 6;
  float ar[64], br[64];
#pragma unroll
  for (int k = 0; k < 64; ++k) {
    ar[k] = eW1[k * 64 + lane];
    br[k] = eW1[(64 + k) * 64 + lane];
  }
  __shared__ __align__(16) float hbuf[4][64];
  float* hb = hbuf[wv];
  const float4* hb4 = (const float4*)hb;

  int nw = gridDim.x * 4;
  int wid = blockIdx.x * 4 + wv;
  int per = (N_NODES + nw - 1) / nw;
  int n0 = wid * per, n1 = min(N_NODES, n0 + per);
  for (int n = n0; n < n1; ++n) {
    hb[lane] = h[n * 64 + lane];
    __builtin_amdgcn_wave_barrier();
    float uu = 0.f, vv = 0.f;
#pragma unroll
    for (int k4 = 0; k4 < 16; ++k4) {
      float4 hh = hb4[k4];
      uu += hh.x * ar[4 * k4 + 0]; vv += hh.x * br[4 * k4 + 0];
      uu += hh.y * ar[4 * k4 + 1]; vv += hh.y * br[4 * k4 + 1];
      uu += hh.z * ar[4 * k4 + 2]; vv += hh.z * br[4 * k4 + 2];
      uu += hh.w * ar[4 * k4 + 3]; vv += hh.w * br[4 * k4 + 3];
    }
    u[n * 64 + lane] = uu;
    v[n * 64 + lane] = vv;
    __builtin_amdgcn_wave_barrier();
  }
}

// ---------------------------------------------------------------------------
// Fused edge kernel, MFMA version. Per wave-tile of 16 edges:
//   phase1: t = silu(u[r]+v[c]+ea*w+b1)  (lane = feature) -> LDS [feat][edge]
//   phase2: e_pre = t @ W2 via split-bf16 MFMA (hi/lo, 3 products ~ fp32)
//   epilogue: e = silu(e_pre + b2); agg[r] += e  (atomics, C/D layout)
// A-frag layout: A[m=lane&15][k=quad*8+j]; C/D: col=lane&15,row=quad*4+reg.
// ---------------------------------------------------------------------------
__global__ __launch_bounds__(256) void k_edge(
    const float* __restrict__ u, const float* __restrict__ v,
    const float* __restrict__ eatt, const int* __restrict__ rows, const int* __restrict__ cols,
    const float* __restrict__ wea, const float* __restrict__ eb1,
    const float* __restrict__ W2, const float* __restrict__ eb2,
    float* __restrict__ agg)
{
  const int lane = threadIdx.x & 63;
  const int wv = threadIdx.x >> 6;
  const int n16 = lane & 15;
  const int quad = lane >> 4;

  // B fragments (W2 columns), split hi/lo, resident in VGPRs.
  short8 Whi[2][4], Wlo[2][4];
#pragma unroll
  for (int s = 0; s < 2; ++s) {
#pragma unroll
    for (int nt = 0; nt < 4; ++nt) {
#pragma unroll
      for (int j = 0; j < 8; ++j) {
        float w2v = W2[(s * 32 + quad * 8 + j) * 64 + nt * 16 + n16];
        short hi = f2bf_s(w2v);
        Whi[s][nt][j] = hi;
        Wlo[s][nt][j] = f2bf_s(w2v - bf_s2f(hi));
      }
    }
  }
  float we = wea[lane];
  float b1v = eb1[lane];
  float b2v[4];
#pragma unroll
  for (int nt = 0; nt < 4; ++nt) b2v[nt] = eb2[nt * 16 + n16];

  __shared__ float Tl[4][64 * 17];   // [feat][edge], pad 17: <=2-way conflicts
  float* T = Tl[wv];

  const int nwaves = gridDim.x * 4;
  const int wid = blockIdx.x * 4 + wv;
  const int ntiles = N_EDGES / 16;   // 25000, exact

  for (int tile = wid; tile < ntiles; tile += nwaves) {
    int e0 = tile * 16;
    int r16 = rows[e0 + n16];
    int c16 = cols[e0 + n16];
    float ea16 = eatt[e0 + n16];

    // phase 1: 16 edges, lane = feature
#pragma unroll 4
    for (int e = 0; e < 16; ++e) {
      int r = __shfl(r16, e);
      int c = __shfl(c16, e);
      float ea = __shfl(ea16, e);
      float t = u[r * 64 + lane] + v[c * 64 + lane] + ea * we + b1v;
      T[lane * 17 + e] = silu_f(t);
    }
    __builtin_amdgcn_wave_barrier();

    f32x4 acc[4] = {};
#pragma unroll
    for (int s = 0; s < 2; ++s) {
      short8 ahi, alo;
#pragma unroll
      for (int j = 0; j < 8; ++j) {
        float tv = T[(s * 32 + quad * 8 + j) * 17 + n16];
        short hi = f2bf_s(tv);
        ahi[j] = hi;
        alo[j] = f2bf_s(tv - bf_s2f(hi));
      }
#pragma unroll
      for (int nt = 0; nt < 4; ++nt) {
        acc[nt] = __builtin_amdgcn_mfma_f32_16x16x32_bf16(ahi, Whi[s][nt], acc[nt], 0, 0, 0);
        acc[nt] = __builtin_amdgcn_mfma_f32_16x16x32_bf16(ahi, Wlo[s][nt], acc[nt], 0, 0, 0);
        acc[nt] = __builtin_amdgcn_mfma_f32_16x16x32_bf16(alo, Whi[s][nt], acc[nt], 0, 0, 0);
      }
    }
    __builtin_amdgcn_wave_barrier();

    // epilogue: silu + atomic scatter-add; D row = quad*4+reg, col = nt*16+n16
#pragma unroll
    for (int reg = 0; reg < 4; ++reg) {
      int m = quad * 4 + reg;
      int r = __shfl(r16, m);
#pragma unroll
      for (int nt = 0; nt < 4; ++nt) {
        float ev = silu_f(acc[nt][reg] + b2v[nt]);
        unsafeAtomicAdd(&agg[r * 64 + nt * 16 + n16], ev);
      }
    }
    __builtin_amdgcn_wave_barrier();
  }
}

// ---------------------------------------------------------------------------
// Per-layer node MLP: h = silu(h@nW1[0:64] + agg@nW1[64:128] + nb1) @ nW2 + nb2
// ---------------------------------------------------------------------------
__global__ __launch_bounds__(256, 2) void k_node_post(
    float* __restrict__ h, const float* __restrict__ agg,
    const float* __restrict__ nW1, const float* __restrict__ nb1,
    const float* __restrict__ nW2, const float* __restrict__ nb2)
{
  const int lane = threadIdx.x & 63;
  const int wv = threadIdx.x >> 6;
  float ar[64], br[64], wr[64];
#pragma unroll
  for (int k = 0; k < 64; ++k) {
    ar[k] = nW1[k * 64 + lane];
    br[k] = nW1[(64 + k) * 64 + lane];
    wr[k] = nW2[k * 64 + lane];
  }
  float b1v = nb1[lane], b2v = nb2[lane];
  __shared__ __align__(16) float hbuf[4][64];
  __shared__ __align__(16) float abuf[4][64];
  __shared__ __align__(16) float tbuf[4][64];
  float* hb = hbuf[wv]; float* ab = abuf[wv]; float* tb = tbuf[wv];
  const float4* hb4 = (const float4*)hb;
  const float4* ab4 = (const float4*)ab;
  const float4* tb4 = (const float4*)tb;

  int nw = gridDim.x * 4;
  int wid = blockIdx.x * 4 + wv;
  int per = (N_NODES + nw - 1) / nw;
  int n0 = wid * per, n1 = min(N_NODES, n0 + per);
  for (int n = n0; n < n1; ++n) {
    hb[lane] = h[n * 64 + lane];
    ab[lane] = agg[n * 64 + lane];
    __builtin_amdgcn_wave_barrier();
    float t = b1v;
#pragma unroll
    for (int k4 = 0; k4 < 16; ++k4) {
      float4 hh = hb4[k4];
      float4 aa = ab4[k4];
      t += hh.x * ar[4 * k4 + 0] + aa.x * br[4 * k4 + 0];
      t += hh.y * ar[4 * k4 + 1] + aa.y * br[4 * k4 + 1];
      t += hh.z * ar[4 * k4 + 2] + aa.z * br[4 * k4 + 2];
      t += hh.w * ar[4 * k4 + 3] + aa.w * br[4 * k4 + 3];
    }
    t = silu_f(t);
    __builtin_amdgcn_wave_barrier();
    tb[lane] = t;
    __builtin_amdgcn_wave_barrier();
    float o = b2v;
#pragma unroll
    for (int k4 = 0; k4 < 16; ++k4) {
      float4 tt = tb4[k4];
      o += tt.x * wr[4 * k4 + 0];
      o += tt.y * wr[4 * k4 + 1];
      o += tt.z * wr[4 * k4 + 2];
      o += tt.w * wr[4 * k4 + 3];
    }
    h[n * 64 + lane] = o;
    __builtin_amdgcn_wave_barrier();
  }
}

// ---------------------------------------------------------------------------
// Final node MLP: out = silu(concat(h,agg) @ dnW1 + dnb1) @ dnW2 + dnb2, (N,4)
// ---------------------------------------------------------------------------
__global__ __launch_bounds__(256, 2) void k_node_final(
    const float* __restrict__ h, const float* __restrict__ agg,
    const float* __restrict__ dnW1, const float* __restrict__ dnb1,
    const float* __restrict__ dnW2, const float* __restrict__ dnb2,
    float* __restrict__ out)
{
  const int lane = threadIdx.x & 63;
  const int wv = threadIdx.x >> 6;
  float ar[64], br[64], wr[64];
#pragma unroll
  for (int k = 0; k < 64; ++k) {
    ar[k] = dnW1[k * 64 + lane];
    br[k] = dnW1[(64 + k) * 64 + lane];
    wr[k] = dnW2[k * 4 + (lane & 3)];
  }
  float b1v = dnb1[lane];
  float b2v = dnb2[lane & 3];
  __shared__ __align__(16) float hbuf[4][64];
  __shared__ __align__(16) float abuf[4][64];
  __shared__ __align__(16) float tbuf[4][64];
  float* hb = hbuf[wv]; float* ab = abuf[wv]; float* tb = tbuf[wv];
  const float4* hb4 = (const float4*)hb;
  const float4* ab4 = (const float4*)ab;
  const float4* tb4 = (const float4*)tb;

  int nw = gridDim.x * 4;
  int wid = blockIdx.x * 4 + wv;
  int per = (N_NODES + nw - 1) / nw;
  int n0 = wid * per, n1 = min(N_NODES, n0 + per);
  for (int n = n0; n < n1; ++n) {
    hb[lane] = h[n * 64 + lane];
    ab[lane] = agg[n * 64 + lane];
    __builtin_amdgcn_wave_barrier();
    float t = b1v;
#pragma unroll
    for (int k4 = 0; k4 < 16; ++k4) {
      float4 hh = hb4[k4];
      float4 aa = ab4[k4];
      t += hh.x * ar[4 * k4 + 0] + aa.x * br[4 * k4 + 0];
      t += hh.y * ar[4 * k4 + 1] + aa.y * br[4 * k4 + 1];
      t += hh.z * ar[4 * k4 + 2] + aa.z * br[4 * k4 + 2];
      t += hh.w * ar[4 * k4 + 3] + aa.w * br[4 * k4 + 3];
    }
    t = silu_f(t);
    __builtin_amdgcn_wave_barrier();
    tb[lane] = t;
    __builtin_amdgcn_wave_barrier();
    float o = b2v;
#pragma unroll
    for (int k4 = 0; k4 < 16; ++k4) {
      float4 tt = tb4[k4];
      o += tt.x * wr[4 * k4 + 0];
      o += tt.y * wr[4 * k4 + 1];
      o += tt.z * wr[4 * k4 + 2];
      o += tt.w * wr[4 * k4 + 3];
    }
    if (lane < 4) out[n * 4 + lane] = o;
    __builtin_amdgcn_wave_barrier();
  }
}

extern "C" void kernel_launch(void* const* d_in, const int* in_sizes, int n_in,
                              void* d_out, int out_size, void* d_ws, size_t ws_size,
                              hipStream_t stream)
{
  const float* nodes = (const float*)d_in[0];
  const int*   edges = (const int*)d_in[1];
  const float* eatt  = (const float*)d_in[2];
  const float* W_emb = (const float*)d_in[3];
  const float* b_emb = (const float*)d_in[4];
  const float* Wg1   = (const float*)d_in[5];
  const float* bg1   = (const float*)d_in[6];
  const float* Wg2   = (const float*)d_in[7];
  const float* bg2   = (const float*)d_in[8];
  const float* eW1   = (const float*)d_in[9];
  const float* eb1   = (const float*)d_in[10];
  const float* eW2   = (const float*)d_in[11];
  const float* eb2   = (const float*)d_in[12];
  const float* nW1   = (const float*)d_in[13];
  const float* nb1   = (const float*)d_in[14];
  const float* nW2   = (const float*)d_in[15];
  const float* nb2   = (const float*)d_in[16];
  const float* deW1  = (const float*)d_in[17];
  const float* deb1  = (const float*)d_in[18];
  const float* deW2  = (const float*)d_in[19];
  const float* deb2  = (const float*)d_in[20];
  const float* dnW1  = (const float*)d_in[21];
  const float* dnb1  = (const float*)d_in[22];
  const float* dnW2  = (const float*)d_in[23];
  const float* dnb2  = (const float*)d_in[24];
  float* out = (float*)d_out;

  float* h   = (float*)d_ws;
  float* u   = h + N_NODES * 64;
  float* v   = u + N_NODES * 64;
  float* agg = v + N_NODES * 64;

  const int* rows = edges;
  const int* cols = edges + N_EDGES;

  k_embed<<<(N_NODES + 31) / 32, 256, 0, stream>>>(nodes, W_emb, b_emb, Wg1, bg1, Wg2, bg2, h);

  for (int i = 0; i < 5; ++i) {
    const float* W1i = eW1 + i * 129 * 64;
    k_node_pre<<<1024, 256, 0, stream>>>(h, W1i, u, v);
    hipMemsetAsync(agg, 0, N_NODES * 64 * sizeof(float), stream);
    k_edge<<<1024, 256, 0, stream>>>(u, v, eatt, rows, cols, W1i + 128 * 64,
                                     eb1 + i * 64, eW2 + i * 64 * 64, eb2 + i * 64, agg);
    k_node_post<<<1024, 256, 0, stream>>>(h, agg, nW1 + i * 128 * 64, nb1 + i * 64,
                                          nW2 + i * 64 * 64, nb2 + i * 64);
  }
  // decoder GCL
  k_node_pre<<<1024, 256, 0, stream>>>(h, deW1, u, v);
  hipMemsetAsync(agg, 0, N_NODES * 64 * sizeof(float), stream);
  k_edge<<<1024, 256, 0, stream>>>(u, v, eatt, rows, cols, deW1 + 128 * 64,
                                   deb1, deW2, deb2, agg);
  k_node_final<<<1024, 256, 0, stream>>>(h, agg, dnW1, dnb1, dnW2, dnb2, out);
}